// Round 1
// baseline (1593.974 us; speedup 1.0000x reference)
//
#include <hip/hip_runtime.h>

// Quant3Linear on MI355X (gfx950)
// out = x @ ((U^T (dq(qweight^T)) V) / scaleWH)^T + bias
// Decomposition (550 GF fp32-equivalent):
//   A1[i,a] = sum_o Dq[i,o] U[o,a]            (G1, 4096^3)
//   WT[j,a] = sum_i V[i,j] A1[i,a] / sWH[j]   (G2, 4096^3)
//   out[m,a] = sum_j x[m,j] WT[j,a] + bias[a] (G3, 8192x4096x4096)
// All GEMMs in bf16x3 split precision (hi/lo pairs, 3 MFMA per k-step).

#define KT128 128   // K/32, K = 4096 for all GEMMs

typedef __attribute__((ext_vector_type(4))) float f32x4;
typedef __attribute__((ext_vector_type(4))) int   i32x4;
typedef __attribute__((ext_vector_type(8))) short s16x8;
typedef __attribute__((ext_vector_type(4))) short s16x4;

__device__ __forceinline__ unsigned short f2bf(float f){
  unsigned u = __builtin_bit_cast(unsigned, f);
  u += 0x7FFFu + ((u >> 16) & 1u);            // round-to-nearest-even
  return (unsigned short)(u >> 16);
}
__device__ __forceinline__ float bf2f(unsigned short h){
  unsigned u = ((unsigned)h) << 16;
  return __builtin_bit_cast(float, u);
}
__device__ __forceinline__ void splitbf(float v, short &hi, short &lo){
  unsigned short h = f2bf(v);
  float r = v - bf2f(h);
  hi = (short)h;
  lo = (short)f2bf(r);
}

__device__ __forceinline__ void stage16(const short* g, short* l){
  __builtin_amdgcn_global_load_lds((const __attribute__((address_space(1))) void*)g,
                                   (__attribute__((address_space(3))) void*)l,
                                   16, 0, 0);
}

// ---------------------------------------------------------------------------
// pack_rows: src[M][4096] -> A-packed [mt][kt][kg][mr][8] bf16 hi/lo.
// chunk(mt,kt,kg,mr) = src[mt*128+mr][kt*32+kg*8 .. +7]
// MODE 0: fp32 passthrough (x). MODE 1: int32 dequant (qweight).
// grid: (128, M/128), block 256.
// ---------------------------------------------------------------------------
template<int MODE>
__global__ __launch_bounds__(256)
void pack_rows_kernel(const void* __restrict__ srcv,
                      const float* __restrict__ scale_p,
                      short* __restrict__ Oh, short* __restrict__ Ol)
{
  __shared__ float lds[128][33];
  const int kt = blockIdx.x;
  const int mt = blockIdx.y;
  const int t  = threadIdx.x;
  float dq_a = 1.0f, dq_b = 0.0f;
  if (MODE == 1){ float sc = scale_p[0]; dq_a = sc * (2.0f/15.0f); dq_b = -sc; }
  const int rrow = t >> 3;   // 0..31
  const int c4   = t & 7;    // 0..7 -> 4 cols each
  #pragma unroll
  for (int rr = 0; rr < 4; ++rr){
    const int row = rr*32 + rrow;
    const size_t soff = ((size_t)(mt*128 + row))*4096 + (size_t)kt*32 + c4*4;
    if (MODE == 0){
      const f32x4 v = *(const f32x4*)((const float*)srcv + soff);
      #pragma unroll
      for (int j=0;j<4;++j) lds[row][c4*4+j] = v[j];
    } else {
      const i32x4 v = *(const i32x4*)((const int*)srcv + soff);
      #pragma unroll
      for (int j=0;j<4;++j) lds[row][c4*4+j] = (float)v[j]*dq_a + dq_b;
    }
  }
  __syncthreads();
  #pragma unroll
  for (int rnd=0; rnd<2; ++rnd){
    const int cc = rnd*256 + t;
    const int kgp = cc >> 7, mr = cc & 127;
    s16x8 h8, l8;
    #pragma unroll
    for (int j=0;j<8;++j){
      short h,l; splitbf(lds[mr][kgp*8+j], h, l);
      h8[j]=h; l8[j]=l;
    }
    const size_t chunk = ((((size_t)mt*KT128 + kt)*4 + kgp)*128 + mr)*8;
    *(s16x8*)(Oh + chunk) = h8;
    *(s16x8*)(Ol + chunk) = l8;
  }
}

// ---------------------------------------------------------------------------
// pack_cols: src[4096][4096] -> packed [xt][kt][kg][xr][8] where
// chunk(xt,kt,kg,xr) = src[kt*32+kg*8 .. +7][xt*128+xr]  (column chunks)
// Used for U (as G1 B-operand) and V (as G2 A-operand: Vt[j][i]=V[i][j]).
// grid: (128, 32), block 256.
// ---------------------------------------------------------------------------
__global__ __launch_bounds__(256)
void pack_cols_kernel(const float* __restrict__ src,
                      short* __restrict__ Oh, short* __restrict__ Ol)
{
  __shared__ float lds[32][132];   // 132: keeps f32x4 stores 16B-aligned, breaks bank stride
  const int kt = blockIdx.x;
  const int xt = blockIdx.y;
  const int t  = threadIdx.x;
  const int o4 = t >> 5;   // 0..7
  const int c4 = t & 31;   // 0..31 -> 4 cols each
  #pragma unroll
  for (int rr=0; rr<4; ++rr){
    const int o = rr*8 + o4;
    const size_t soff = ((size_t)(kt*32 + o))*4096 + (size_t)xt*128 + c4*4;
    const f32x4 v = *(const f32x4*)(src + soff);
    *(f32x4*)&lds[o][c4*4] = v;
  }
  __syncthreads();
  #pragma unroll
  for (int rnd=0; rnd<2; ++rnd){
    const int cc = rnd*256 + t;
    const int kgp = cc >> 7, xr = cc & 127;
    s16x8 h8, l8;
    #pragma unroll
    for (int j=0;j<8;++j){
      short h,l; splitbf(lds[kgp*8+j][xr], h, l);
      h8[j]=h; l8[j]=l;
    }
    const size_t chunk = ((((size_t)xt*KT128 + kt)*4 + kgp)*128 + xr)*8;
    *(s16x8*)(Oh + chunk) = h8;
    *(s16x8*)(Ol + chunk) = l8;
  }
}

// ---------------------------------------------------------------------------
// GEMM C[M,N] = (Ah+Al)[M,K] @ (Bh+Bl)[K,N], packed operands, bf16x3.
// 128x128 tile, 4 waves (2x2), 4x4 frags of mfma_f32_16x16x32_bf16 each.
// EPI 0: write C as next-stage B-packed hi/lo, optional per-row 1/rowScale.
// EPI 1: write fp32 out[M][4096] + bias[n].
// grid: (N/128, M/128), block 256.
// ---------------------------------------------------------------------------
template<int EPI>
__global__ __launch_bounds__(256, 2)
void gemm_bf16x3(const short* __restrict__ Ah, const short* __restrict__ Al,
                 const short* __restrict__ Bh, const short* __restrict__ Bl,
                 float* __restrict__ outF, const float* __restrict__ bias,
                 short* __restrict__ Oh, short* __restrict__ Ol,
                 const float* __restrict__ rowScale)
{
  __shared__ short ls[16384];               // 32 KiB: Ah,Al,Bh,Bl tiles (4KB shorts each)
  short* lsAh = ls;
  short* lsAl = ls + 4096;
  short* lsBh = ls + 8192;
  short* lsBl = ls + 12288;

  const int t    = threadIdx.x;
  const int lane = t & 63, wave = t >> 6;
  const int wr   = wave >> 1, wc = wave & 1;
  const int nt   = blockIdx.x, mt = blockIdx.y;
  const int lr   = lane & 15, kg = lane >> 4;

  f32x4 acc[4][4];
  #pragma unroll
  for (int i=0;i<4;++i)
    #pragma unroll
    for (int j=0;j<4;++j)
      acc[i][j] = f32x4{0.f,0.f,0.f,0.f};

  const short* bAh = Ah + ((size_t)mt*KT128)*4096;
  const short* bAl = Al + ((size_t)mt*KT128)*4096;
  const short* bBh = Bh + ((size_t)nt*KT128)*4096;
  const short* bBl = Bl + ((size_t)nt*KT128)*4096;

  for (int kt = 0; kt < KT128; ++kt){
    const size_t to = (size_t)kt*4096;
    #pragma unroll
    for (int rnd=0; rnd<2; ++rnd){
      const int lo_ = rnd*2048 + wave*512;  // wave-uniform LDS short offset
      const int go  = lo_ + lane*8;         // matching per-lane global offset
      stage16(bAh + to + go, lsAh + lo_);
      stage16(bAl + to + go, lsAl + lo_);
      stage16(bBh + to + go, lsBh + lo_);
      stage16(bBl + to + go, lsBl + lo_);
    }
    __syncthreads();

    s16x8 a_h[4], a_l[4];
    #pragma unroll
    for (int fm=0; fm<4; ++fm){
      const int row = wr*64 + fm*16 + lr;
      a_h[fm] = *(const s16x8*)(lsAh + (kg*128 + row)*8);
      a_l[fm] = *(const s16x8*)(lsAl + (kg*128 + row)*8);
    }
    #pragma unroll
    for (int fn=0; fn<4; ++fn){
      const int col = wc*64 + fn*16 + lr;
      const s16x8 b_h = *(const s16x8*)(lsBh + (kg*128 + col)*8);
      const s16x8 b_l = *(const s16x8*)(lsBl + (kg*128 + col)*8);
      #pragma unroll
      for (int fm=0; fm<4; ++fm){
        f32x4 c = acc[fm][fn];
        c = __builtin_amdgcn_mfma_f32_16x16x32_bf16(a_h[fm], b_h, c, 0,0,0);
        c = __builtin_amdgcn_mfma_f32_16x16x32_bf16(a_h[fm], b_l, c, 0,0,0);
        c = __builtin_amdgcn_mfma_f32_16x16x32_bf16(a_l[fm], b_h, c, 0,0,0);
        acc[fm][fn] = c;
      }
    }
    __syncthreads();
  }

  const int r0 = (lane >> 4) * 4;           // C/D: row=(l>>4)*4+reg, col=l&15
  if (EPI == 1){
    #pragma unroll
    for (int fm=0; fm<4; ++fm){
      const int gm = mt*128 + wr*64 + fm*16 + r0;
      #pragma unroll
      for (int fn=0; fn<4; ++fn){
        const int gn = nt*128 + wc*64 + fn*16 + lr;
        const float b = bias[gn];
        #pragma unroll
        for (int reg=0; reg<4; ++reg)
          outF[(size_t)(gm+reg)*4096 + gn] = acc[fm][fn][reg] + b;
      }
    }
  } else {
    #pragma unroll
    for (int fm=0; fm<4; ++fm){
      const int rowBase = mt*128 + wr*64 + fm*16 + r0;   // global m (next-stage k)
      float rs[4];
      #pragma unroll
      for (int reg=0; reg<4; ++reg)
        rs[reg] = rowScale ? (1.0f / rowScale[rowBase+reg]) : 1.0f;
      const int ktp = rowBase >> 5;
      const int kgp = (rowBase >> 3) & 3;
      const int rp  = rowBase & 7;                        // 0 or 4
      #pragma unroll
      for (int fn=0; fn<4; ++fn){
        const int nr = wc*64 + fn*16 + lr;
        const size_t chunk = ((((size_t)nt*KT128 + ktp)*4 + kgp)*128 + nr)*8 + rp;
        s16x4 h4, l4;
        #pragma unroll
        for (int reg=0; reg<4; ++reg){
          short h,l; splitbf(acc[fm][fn][reg]*rs[reg], h, l);
          h4[reg]=h; l4[reg]=l;
        }
        *(s16x4*)(Oh + chunk) = h4;
        *(s16x4*)(Ol + chunk) = l4;
      }
    }
  }
}

// ---------------------------------------------------------------------------
extern "C" void kernel_launch(void* const* d_in, const int* in_sizes, int n_in,
                              void* d_out, int out_size, void* d_ws, size_t ws_size,
                              hipStream_t stream)
{
  const float* x      = (const float*)d_in[0];   // [4,2048,4096]
  const int*   qw     = (const int*)  d_in[1];   // [4096,4096]
  const float* scale  = (const float*)d_in[2];   // [1]
  const float* sWH    = (const float*)d_in[3];   // [4096]
  const float* bias   = (const float*)d_in[4];   // [4096]
  const float* U      = (const float*)d_in[5];   // [4096,4096]
  const float* V      = (const float*)d_in[6];   // [4096,4096]
  float* out = (float*)d_out;

  const size_t SZW = (size_t)4096*4096;          // shorts per 4096^2 bf16 buffer
  if (ws_size < 6*SZW*sizeof(short)) return;     // need 202 MB workspace

  short* ws  = (short*)d_ws;
  short* Dh  = ws;            // slot0: Dq hi   -> later V hi, then Xl half
  short* Dl  = ws + SZW;      // slot1: Dq lo   -> later V lo, then Xl half
  short* Uh  = ws + 2*SZW;    // slot2: U hi    -> later W hi
  short* Ul  = ws + 3*SZW;    // slot3: U lo    -> later W lo
  short* A1h = ws + 4*SZW;    // slot4: A1 hi   -> later Xh half
  short* A1l = ws + 5*SZW;    // slot5: A1 lo   -> later Xh half
  short* Xh  = ws + 4*SZW;    // spans slots 4,5 (A1 dead after G2)
  short* Xl  = ws;            // spans slots 0,1 (V dead after G2)

  dim3 blk(256);

  // 1) dequant+pack qweight rows -> Dq packed-A
  pack_rows_kernel<1><<<dim3(128,32), blk, 0, stream>>>((const void*)qw, scale, Dh, Dl);
  // 2) pack U columns -> packed-B
  pack_cols_kernel<<<dim3(128,32), blk, 0, stream>>>(U, Uh, Ul);
  // 3) G1: A1 = Dq @ U  -> packed-B for G2
  gemm_bf16x3<0><<<dim3(32,32), blk, 0, stream>>>(Dh, Dl, Uh, Ul,
                                                  nullptr, nullptr, A1h, A1l, nullptr);
  // 4) pack V columns -> packed-A (Vt)   [reuses Dq slots]
  pack_cols_kernel<<<dim3(128,32), blk, 0, stream>>>(V, Dh, Dl);
  // 5) G2: WT = Vt @ A1, rows /= scaleWH -> packed-B for G3  [into U slots]
  gemm_bf16x3<0><<<dim3(32,32), blk, 0, stream>>>(Dh, Dl, A1h, A1l,
                                                  nullptr, nullptr, Uh, Ul, sWH);
  // 6) pack x rows -> packed-A  [Xh over A1 slots, Xl over V slots]
  pack_rows_kernel<0><<<dim3(128,64), blk, 0, stream>>>((const void*)x, nullptr, Xh, Xl);
  // 7) G3: out = x @ WT + bias
  gemm_bf16x3<1><<<dim3(32,64), blk, 0, stream>>>(Xh, Xl, Uh, Ul,
                                                  out, bias, nullptr, nullptr, nullptr);
}

// Round 2
// 1569.356 us; speedup vs baseline: 1.0157x; 1.0157x over previous
//
#include <hip/hip_runtime.h>

// Quant3Linear on MI355X (gfx950)
// out = x @ ((U^T (dq(qweight^T)) V) / scaleWH)^T + bias
// Decomposition (1237 GF bf16 after G1-x2):
//   A1[i,a] = sum_o Dqint[i,o] U[o,a] * (scale/15)   (G1, 4096^3, bf16x2: A exact int)
//   WT[j,a] = sum_i V[i,j] A1[i,a] / sWH[j]          (G2, 4096^3, bf16x3)
//   out[m,a] = sum_j x[m,j] WT[j,a] + bias[a]        (G3, 8192x4096x4096, bf16x3)

#define KT128 128   // K/32, K = 4096 for all GEMMs

typedef __attribute__((ext_vector_type(4))) float f32x4;
typedef __attribute__((ext_vector_type(4))) int   i32x4;
typedef __attribute__((ext_vector_type(8))) short s16x8;
typedef __attribute__((ext_vector_type(4))) short s16x4;

__device__ __forceinline__ unsigned short f2bf(float f){
  unsigned u = __builtin_bit_cast(unsigned, f);
  u += 0x7FFFu + ((u >> 16) & 1u);            // round-to-nearest-even
  return (unsigned short)(u >> 16);
}
__device__ __forceinline__ float bf2f(unsigned short h){
  unsigned u = ((unsigned)h) << 16;
  return __builtin_bit_cast(float, u);
}
__device__ __forceinline__ void splitbf(float v, short &hi, short &lo){
  unsigned short h = f2bf(v);
  float r = v - bf2f(h);
  hi = (short)h;
  lo = (short)f2bf(r);
}

__device__ __forceinline__ void stage16(const short* g, short* l){
  __builtin_amdgcn_global_load_lds((const __attribute__((address_space(1))) void*)g,
                                   (__attribute__((address_space(3))) void*)l,
                                   16, 0, 0);
}

// XCD-aware bijective block swizzle (all grids have nwg % 8 == 0).
__device__ __forceinline__ void swz_tile(int &nt, int &mt){
  const int gx   = gridDim.x;
  const int nwg  = gx * gridDim.y;
  const int orig = blockIdx.y * gx + blockIdx.x;
  const int cpx  = nwg >> 3;
  const int s    = (orig & 7) * cpx + (orig >> 3);
  nt = s % gx;
  mt = s / gx;
}

// ---------------------------------------------------------------------------
// pack_rows: src[M][4096] -> A-packed [mt][kt][kg][mr][8] bf16 hi/lo.
// MODE 0: fp32 split hi/lo (x). MODE 1: int32 -> exact integer bf16 (2q-15),
//         hi only (lo == 0 by construction).
// grid: (128, M/128), block 256.
// ---------------------------------------------------------------------------
template<int MODE>
__global__ __launch_bounds__(256)
void pack_rows_kernel(const void* __restrict__ srcv,
                      short* __restrict__ Oh, short* __restrict__ Ol)
{
  __shared__ float lds[128][33];
  const int kt = blockIdx.x;
  const int mt = blockIdx.y;
  const int t  = threadIdx.x;
  const int rrow = t >> 3;   // 0..31
  const int c4   = t & 7;    // 0..7 -> 4 cols each
  #pragma unroll
  for (int rr = 0; rr < 4; ++rr){
    const int row = rr*32 + rrow;
    const size_t soff = ((size_t)(mt*128 + row))*4096 + (size_t)kt*32 + c4*4;
    if (MODE == 0){
      const f32x4 v = *(const f32x4*)((const float*)srcv + soff);
      #pragma unroll
      for (int j=0;j<4;++j) lds[row][c4*4+j] = v[j];
    } else {
      const i32x4 v = *(const i32x4*)((const int*)srcv + soff);
      #pragma unroll
      for (int j=0;j<4;++j) lds[row][c4*4+j] = (float)(2*v[j] - 15);  // exact in bf16
    }
  }
  __syncthreads();
  #pragma unroll
  for (int rnd=0; rnd<2; ++rnd){
    const int cc = rnd*256 + t;
    const int kgp = cc >> 7, mr = cc & 127;
    s16x8 h8, l8;
    #pragma unroll
    for (int j=0;j<8;++j){
      if (MODE == 1){
        h8[j] = (short)f2bf(lds[mr][kgp*8+j]);   // exact, no lo
      } else {
        short h,l; splitbf(lds[mr][kgp*8+j], h, l);
        h8[j]=h; l8[j]=l;
      }
    }
    const size_t chunk = ((((size_t)mt*KT128 + kt)*4 + kgp)*128 + mr)*8;
    *(s16x8*)(Oh + chunk) = h8;
    if (MODE == 0) *(s16x8*)(Ol + chunk) = l8;
  }
}

// ---------------------------------------------------------------------------
// pack_cols: src[4096][4096] -> packed [xt][kt][kg][xr][8], chunk =
// src[kt*32+kg*8 .. +7][xt*128+xr]. Used for U (G1 B) and V (G2 A = V^T).
// grid: (128, 32), block 256.
// ---------------------------------------------------------------------------
__global__ __launch_bounds__(256)
void pack_cols_kernel(const float* __restrict__ src,
                      short* __restrict__ Oh, short* __restrict__ Ol)
{
  __shared__ float lds[32][132];
  const int kt = blockIdx.x;
  const int xt = blockIdx.y;
  const int t  = threadIdx.x;
  const int o4 = t >> 5;   // 0..7
  const int c4 = t & 31;   // 0..31 -> 4 cols each
  #pragma unroll
  for (int rr=0; rr<4; ++rr){
    const int o = rr*8 + o4;
    const size_t soff = ((size_t)(kt*32 + o))*4096 + (size_t)xt*128 + c4*4;
    const f32x4 v = *(const f32x4*)(src + soff);
    *(f32x4*)&lds[o][c4*4] = v;
  }
  __syncthreads();
  #pragma unroll
  for (int rnd=0; rnd<2; ++rnd){
    const int cc = rnd*256 + t;
    const int kgp = cc >> 7, xr = cc & 127;
    s16x8 h8, l8;
    #pragma unroll
    for (int j=0;j<8;++j){
      short h,l; splitbf(lds[kgp*8+j][xr], h, l);
      h8[j]=h; l8[j]=l;
    }
    const size_t chunk = ((((size_t)xt*KT128 + kt)*4 + kgp)*128 + xr)*8;
    *(s16x8*)(Oh + chunk) = h8;
    *(s16x8*)(Ol + chunk) = l8;
  }
}

// ---------------------------------------------------------------------------
// GEMM C[M,N] = A @ B^T-packed, bf16 split precision.
// NMUL=3: (Ah+Al)(Bh+Bl) keep 3 products. NMUL=2: A exact (Al==0), 2 products.
// 128x128 tile, 4 waves (2x2), 4x4 frags of mfma_f32_16x16x32_bf16.
// EPI 0: write C as next-stage B-packed hi/lo, scaled by kmul/rowScale[row].
// EPI 1: write fp32 out[M][4096] + bias[n].
// grid: (N/128, M/128), block 256, XCD-swizzled.
// ---------------------------------------------------------------------------
template<int EPI, int NMUL>
__global__ __launch_bounds__(256, 4)
void gemm_bf16x(const short* __restrict__ Ah, const short* __restrict__ Al,
                const short* __restrict__ Bh, const short* __restrict__ Bl,
                float* __restrict__ outF, const float* __restrict__ bias,
                short* __restrict__ Oh, short* __restrict__ Ol,
                const float* __restrict__ rowScale,
                const float* __restrict__ kmul)
{
  __shared__ short ls[(NMUL==2) ? 12288 : 16384];
  short* lsAh = ls;
  short* lsAl = (NMUL==3) ? (ls + 4096) : nullptr;
  short* lsBh = ls + ((NMUL==2) ? 4096 : 8192);
  short* lsBl = ls + ((NMUL==2) ? 8192 : 12288);

  const int t    = threadIdx.x;
  const int lane = t & 63, wave = t >> 6;
  const int wr   = wave >> 1, wc = wave & 1;
  int nt, mt;
  swz_tile(nt, mt);
  const int lr   = lane & 15, kg = lane >> 4;

  f32x4 acc[4][4];
  #pragma unroll
  for (int i=0;i<4;++i)
    #pragma unroll
    for (int j=0;j<4;++j)
      acc[i][j] = f32x4{0.f,0.f,0.f,0.f};

  const short* bAh = Ah + ((size_t)mt*KT128)*4096;
  const short* bAl = (NMUL==3) ? (Al + ((size_t)mt*KT128)*4096) : nullptr;
  const short* bBh = Bh + ((size_t)nt*KT128)*4096;
  const short* bBl = Bl + ((size_t)nt*KT128)*4096;

  for (int kt = 0; kt < KT128; ++kt){
    const size_t to = (size_t)kt*4096;
    #pragma unroll
    for (int rnd=0; rnd<2; ++rnd){
      const int lo_ = rnd*2048 + wave*512;  // wave-uniform LDS short offset
      const int go  = lo_ + lane*8;         // matching per-lane global offset
      stage16(bAh + to + go, lsAh + lo_);
      if (NMUL==3) stage16(bAl + to + go, lsAl + lo_);
      stage16(bBh + to + go, lsBh + lo_);
      stage16(bBl + to + go, lsBl + lo_);
    }
    __syncthreads();

    // Cache B fragments (32 VGPR), stream A fragments (keeps combined regs <=128)
    s16x8 b_h[4], b_l[4];
    #pragma unroll
    for (int fn=0; fn<4; ++fn){
      const int col = wc*64 + fn*16 + lr;
      b_h[fn] = *(const s16x8*)(lsBh + (kg*128 + col)*8);
      b_l[fn] = *(const s16x8*)(lsBl + (kg*128 + col)*8);
    }
    #pragma unroll
    for (int fm=0; fm<4; ++fm){
      const int row = wr*64 + fm*16 + lr;
      const s16x8 a_h = *(const s16x8*)(lsAh + (kg*128 + row)*8);
      s16x8 a_l;
      if (NMUL==3) a_l = *(const s16x8*)(lsAl + (kg*128 + row)*8);
      #pragma unroll
      for (int fn=0; fn<4; ++fn){
        f32x4 c = acc[fm][fn];
        c = __builtin_amdgcn_mfma_f32_16x16x32_bf16(a_h, b_h[fn], c, 0,0,0);
        c = __builtin_amdgcn_mfma_f32_16x16x32_bf16(a_h, b_l[fn], c, 0,0,0);
        if (NMUL==3)
          c = __builtin_amdgcn_mfma_f32_16x16x32_bf16(a_l, b_h[fn], c, 0,0,0);
        acc[fm][fn] = c;
      }
    }
    __syncthreads();
  }

  const int r0 = (lane >> 4) * 4;           // C/D: row=(l>>4)*4+reg, col=l&15
  if (EPI == 1){
    #pragma unroll
    for (int fm=0; fm<4; ++fm){
      const int gm = mt*128 + wr*64 + fm*16 + r0;
      #pragma unroll
      for (int fn=0; fn<4; ++fn){
        const int gn = nt*128 + wc*64 + fn*16 + lr;
        const float b = bias[gn];
        #pragma unroll
        for (int reg=0; reg<4; ++reg)
          outF[(size_t)(gm+reg)*4096 + gn] = acc[fm][fn][reg] + b;
      }
    }
  } else {
    const float km = kmul ? (kmul[0] * (1.0f/15.0f)) : 1.0f;
    #pragma unroll
    for (int fm=0; fm<4; ++fm){
      const int rowBase = mt*128 + wr*64 + fm*16 + r0;   // global m (next-stage k)
      float rs[4];
      #pragma unroll
      for (int reg=0; reg<4; ++reg)
        rs[reg] = km * (rowScale ? (1.0f / rowScale[rowBase+reg]) : 1.0f);
      const int ktp = rowBase >> 5;
      const int kgp = (rowBase >> 3) & 3;
      const int rp  = rowBase & 7;                        // 0 or 4
      #pragma unroll
      for (int fn=0; fn<4; ++fn){
        const int nr = wc*64 + fn*16 + lr;
        const size_t chunk = ((((size_t)nt*KT128 + ktp)*4 + kgp)*128 + nr)*8 + rp;
        s16x4 h4, l4;
        #pragma unroll
        for (int reg=0; reg<4; ++reg){
          short h,l; splitbf(acc[fm][fn][reg]*rs[reg], h, l);
          h4[reg]=h; l4[reg]=l;
        }
        *(s16x4*)(Oh + chunk) = h4;
        *(s16x4*)(Ol + chunk) = l4;
      }
    }
  }
}

// ---------------------------------------------------------------------------
extern "C" void kernel_launch(void* const* d_in, const int* in_sizes, int n_in,
                              void* d_out, int out_size, void* d_ws, size_t ws_size,
                              hipStream_t stream)
{
  const float* x      = (const float*)d_in[0];   // [4,2048,4096]
  const int*   qw     = (const int*)  d_in[1];   // [4096,4096]
  const float* scale  = (const float*)d_in[2];   // [1]
  const float* sWH    = (const float*)d_in[3];   // [4096]
  const float* bias   = (const float*)d_in[4];   // [4096]
  const float* U      = (const float*)d_in[5];   // [4096,4096]
  const float* V      = (const float*)d_in[6];   // [4096,4096]
  float* out = (float*)d_out;

  const size_t SZW = (size_t)4096*4096;          // shorts per 4096^2 bf16 buffer
  if (ws_size < 6*SZW*sizeof(short)) return;     // need 202 MB workspace

  short* ws  = (short*)d_ws;
  short* Dh  = ws;            // slot0: Dq_int hi -> later V hi, then Xl half
  short* Dl  = ws + SZW;      // slot1: (unused)  -> later V lo, then Xl half
  short* Uh  = ws + 2*SZW;    // slot2: U hi      -> later W hi
  short* Ul  = ws + 3*SZW;    // slot3: U lo      -> later W lo
  short* A1h = ws + 4*SZW;    // slot4: A1 hi     -> later Xh half
  short* A1l = ws + 5*SZW;    // slot5: A1 lo     -> later Xh half
  short* Xh  = ws + 4*SZW;    // spans slots 4,5 (A1 dead after G2)
  short* Xl  = ws;            // spans slots 0,1 (V dead after G2)

  dim3 blk(256);

  // 1) dequant+pack qweight rows -> exact-integer bf16 packed-A (hi only)
  pack_rows_kernel<1><<<dim3(128,32), blk, 0, stream>>>((const void*)qw, Dh, nullptr);
  // 2) pack U columns -> packed-B (hi/lo)
  pack_cols_kernel<<<dim3(128,32), blk, 0, stream>>>(U, Uh, Ul);
  // 3) G1 (x2): A1 = Dq_int @ U * (scale/15)  -> packed-B for G2
  gemm_bf16x<0,2><<<dim3(32,32), blk, 0, stream>>>(Dh, nullptr, Uh, Ul,
                                                   nullptr, nullptr, A1h, A1l,
                                                   nullptr, scale);
  // 4) pack V columns -> packed-A (V^T)   [reuses Dq slots]
  pack_cols_kernel<<<dim3(128,32), blk, 0, stream>>>(V, Dh, Dl);
  // 5) G2 (x3): WT = V^T @ A1, rows /= scaleWH -> packed-B for G3 [into U slots]
  gemm_bf16x<0,3><<<dim3(32,32), blk, 0, stream>>>(Dh, Dl, A1h, A1l,
                                                   nullptr, nullptr, Uh, Ul,
                                                   sWH, nullptr);
  // 6) pack x rows -> packed-A (hi/lo) [Xh over A1 slots, Xl over V slots]
  pack_rows_kernel<0><<<dim3(128,64), blk, 0, stream>>>((const void*)x, Xh, Xl);
  // 7) G3 (x3): out = x @ WT + bias
  gemm_bf16x<1,3><<<dim3(32,64), blk, 0, stream>>>(Xh, Xl, Uh, Ul,
                                                   out, bias, nullptr, nullptr,
                                                   nullptr, nullptr);
}